// Round 2
// baseline (1080.203 us; speedup 1.0000x reference)
//
#include <hip/hip_runtime.h>
#include <hip/hip_bf16.h>

#define NT 8192   // tokens = B*S
#define NH 1024   // hidden
#define NF 2048   // ffn
#define NE 8      // experts
#define NROWS (NT * 2)  // total (token, expert) rows, K=2

typedef short bf16x8 __attribute__((ext_vector_type(8)));
typedef float f32x4 __attribute__((ext_vector_type(4)));

__device__ __forceinline__ void gload16(const void* g, void* l) {
  __builtin_amdgcn_global_load_lds(
      (const __attribute__((address_space(1))) unsigned int*)g,
      (__attribute__((address_space(3))) unsigned int*)l, 16, 0, 0);
}

__device__ __forceinline__ unsigned short f2bf(float f) {
  __hip_bfloat16 h = __float2bfloat16(f);
  return *reinterpret_cast<unsigned short*>(&h);
}

// ---------------- conversion kernels ----------------
__global__ void k_convert_x(const float* __restrict__ in, unsigned short* __restrict__ out) {
  const int i = blockIdx.x * blockDim.x + threadIdx.x;  // one thread per 4 floats
  const float4 v = reinterpret_cast<const float4*>(in)[i];
  ushort4 u;
  u.x = f2bf(v.x); u.y = f2bf(v.y); u.z = f2bf(v.z); u.w = f2bf(v.w);
  reinterpret_cast<ushort4*>(out)[i] = u;
}

// in: [E][R][C] fp32  ->  out: [E][C][R] bf16   (R,C multiples of 32)
__global__ void k_transpose_convert(const float* __restrict__ in, unsigned short* __restrict__ out,
                                    int R, int C) {
  __shared__ float tile[32][33];
  const int e = blockIdx.z;
  const int c0 = blockIdx.x * 32, r0 = blockIdx.y * 32;
  const float* src = in + (size_t)e * R * C;
  unsigned short* dst = out + (size_t)e * R * C;
  const int tx = threadIdx.x, ty = threadIdx.y;  // (32, 8)
#pragma unroll
  for (int i = 0; i < 4; ++i)
    tile[ty + 8 * i][tx] = src[(size_t)(r0 + ty + 8 * i) * C + (c0 + tx)];
  __syncthreads();
#pragma unroll
  for (int i = 0; i < 4; ++i)
    dst[(size_t)(c0 + ty + 8 * i) * R + (r0 + tx)] = f2bf(tile[tx][ty + 8 * i]);
}

// ---------------- routing ----------------
__global__ void k_router(const float* __restrict__ x, const float* __restrict__ wrt,
                         int* __restrict__ top_e, float* __restrict__ top_w,
                         int* __restrict__ cnt) {
  const int t = blockIdx.x * 4 + (threadIdx.x >> 6);
  const int lane = threadIdx.x & 63;
  const float* xr = x + (size_t)t * NH;
  float acc[NE];
#pragma unroll
  for (int e = 0; e < NE; ++e) acc[e] = 0.f;
  for (int h = lane; h < NH; h += 64) {
    const float xv = xr[h];
    const float4 wa = *reinterpret_cast<const float4*>(&wrt[h * NE]);
    const float4 wb = *reinterpret_cast<const float4*>(&wrt[h * NE + 4]);
    acc[0] += xv * wa.x; acc[1] += xv * wa.y; acc[2] += xv * wa.z; acc[3] += xv * wa.w;
    acc[4] += xv * wb.x; acc[5] += xv * wb.y; acc[6] += xv * wb.z; acc[7] += xv * wb.w;
  }
#pragma unroll
  for (int e = 0; e < NE; ++e)
#pragma unroll
    for (int off = 32; off > 0; off >>= 1) acc[e] += __shfl_xor(acc[e], off, 64);
  if (lane == 0) {
    int e0 = 0; float l0 = acc[0];
#pragma unroll
    for (int e = 1; e < NE; ++e) if (acc[e] > l0) { l0 = acc[e]; e0 = e; }  // ties -> lowest idx, like lax.top_k
    int e1 = -1; float l1 = -3.4e38f;
#pragma unroll
    for (int e = 0; e < NE; ++e) if (e != e0 && acc[e] > l1) { l1 = acc[e]; e1 = e; }
    const float ex = expf(l1 - l0);
    const float s = 1.f / (1.f + ex);
    top_e[t * 2 + 0] = e0; top_e[t * 2 + 1] = e1;
    top_w[t * 2 + 0] = s;  top_w[t * 2 + 1] = ex * s;
    atomicAdd(&cnt[e0], 1); atomicAdd(&cnt[e1], 1);
  }
}

__global__ void k_prefix(const int* __restrict__ cnt, int* __restrict__ base,
                         int* __restrict__ cursor) {
  if (threadIdx.x == 0 && blockIdx.x == 0) {
    int s = 0;
    for (int e = 0; e < NE; ++e) { base[e] = s; cursor[e] = s; s += cnt[e]; }
    base[NE] = s;
  }
}

__global__ void k_scatter(const int* __restrict__ top_e, const float* __restrict__ top_w,
                          int* __restrict__ cursor, int* __restrict__ rowmap,
                          float* __restrict__ roww) {
  const int t = blockIdx.x * blockDim.x + threadIdx.x;
  if (t >= NT) return;
#pragma unroll
  for (int k = 0; k < 2; ++k) {
    const int e = top_e[t * 2 + k];
    const int pos = atomicAdd(&cursor[e], 1);
    rowmap[pos] = t;
    roww[pos] = top_w[t * 2 + k];
  }
}

// ---------------- GEMM1: hmid = silu(x@w0) * (x@w1), gathered rows ----------------
// tile 128x128, BK=64, 4 waves; A gathered from xb via rowmap; B from transposed [F][H] weights
__launch_bounds__(256, 2)
__global__ void k_gemm1(const unsigned short* __restrict__ xb,
                        const unsigned short* __restrict__ w0t,
                        const unsigned short* __restrict__ w1t,
                        unsigned short* __restrict__ hmid,
                        const int* __restrict__ rowmap,
                        const int* __restrict__ ebase,
                        const int* __restrict__ ecnt) {
  const int e = blockIdx.z;
  const int cnt = ecnt[e];
  const int rt = blockIdx.x, nt = blockIdx.y;
  if (rt * 128 >= cnt) return;
  __shared__ __align__(16) unsigned short As[128 * 64];
  __shared__ __align__(16) unsigned short B0s[128 * 64];
  __shared__ __align__(16) unsigned short B1s[128 * 64];
  const int tid = threadIdx.x;
  const int lane = tid & 63, wid = tid >> 6;
  const int eb = ebase[e];
  const int rsub = lane >> 3;       // row within 8-row staging chunk
  const int csub = (lane & 7) * 8;  // bf16 col offset within 64

  const unsigned short* ap[4];
  const unsigned short* b0p[4];
  const unsigned short* b1p[4];
#pragma unroll
  for (int i = 0; i < 4; ++i) {
    const int r = (wid * 4 + i) * 8 + rsub;  // tile row 0..127
    int lr = rt * 128 + r;
    if (lr >= cnt) lr = cnt - 1;             // clamp: loads valid, results discarded
    const int tok = rowmap[eb + lr];
    ap[i] = xb + (size_t)tok * NH + csub;
    const int n = nt * 128 + r;
    b0p[i] = w0t + ((size_t)e * NF + n) * NH + csub;
    b1p[i] = w1t + ((size_t)e * NF + n) * NH + csub;
  }
  const int wr = wid >> 1, wn = wid & 1;
  f32x4 acc0[4][4] = {};
  f32x4 acc1[4][4] = {};

  for (int kh = 0; kh < NH; kh += 64) {
    __syncthreads();
#pragma unroll
    for (int i = 0; i < 4; ++i) gload16(ap[i] + kh, &As[(wid * 4 + i) * 8 * 64]);
#pragma unroll
    for (int i = 0; i < 4; ++i) gload16(b0p[i] + kh, &B0s[(wid * 4 + i) * 8 * 64]);
#pragma unroll
    for (int i = 0; i < 4; ++i) gload16(b1p[i] + kh, &B1s[(wid * 4 + i) * 8 * 64]);
    __syncthreads();
#pragma unroll
    for (int ks = 0; ks < 2; ++ks) {
      const int ko = ks * 32 + (lane >> 4) * 8;
      bf16x8 a[4], b0[4], b1[4];
#pragma unroll
      for (int mi = 0; mi < 4; ++mi)
        a[mi] = *reinterpret_cast<const bf16x8*>(&As[(wr * 64 + mi * 16 + (lane & 15)) * 64 + ko]);
#pragma unroll
      for (int ni = 0; ni < 4; ++ni) {
        b0[ni] = *reinterpret_cast<const bf16x8*>(&B0s[(wn * 64 + ni * 16 + (lane & 15)) * 64 + ko]);
        b1[ni] = *reinterpret_cast<const bf16x8*>(&B1s[(wn * 64 + ni * 16 + (lane & 15)) * 64 + ko]);
      }
#pragma unroll
      for (int mi = 0; mi < 4; ++mi)
#pragma unroll
        for (int ni = 0; ni < 4; ++ni) {
          acc0[mi][ni] = __builtin_amdgcn_mfma_f32_16x16x32_bf16(a[mi], b0[ni], acc0[mi][ni], 0, 0, 0);
          acc1[mi][ni] = __builtin_amdgcn_mfma_f32_16x16x32_bf16(a[mi], b1[ni], acc1[mi][ni], 0, 0, 0);
        }
    }
  }
  // epilogue: hmid = silu(g) * u, C/D layout col=lane&15, row=(lane>>4)*4+reg
#pragma unroll
  for (int mi = 0; mi < 4; ++mi)
#pragma unroll
    for (int ni = 0; ni < 4; ++ni)
#pragma unroll
      for (int r = 0; r < 4; ++r) {
        const int lr = rt * 128 + wr * 64 + mi * 16 + (lane >> 4) * 4 + r;
        if (lr >= cnt) continue;
        const int col = nt * 128 + wn * 64 + ni * 16 + (lane & 15);
        const float g = acc0[mi][ni][r], u = acc1[mi][ni][r];
        const float hv = g / (1.f + __expf(-g)) * u;
        hmid[(size_t)(eb + lr) * NF + col] = f2bf(hv);
      }
}

// ---------------- GEMM2: out += gate_w * (hmid @ wo) ----------------
__launch_bounds__(256, 2)
__global__ void k_gemm2(const unsigned short* __restrict__ hmid,
                        const unsigned short* __restrict__ wot,
                        float* __restrict__ out,
                        const int* __restrict__ rowmap,
                        const float* __restrict__ roww,
                        const int* __restrict__ ebase,
                        const int* __restrict__ ecnt) {
  const int e = blockIdx.z;
  const int cnt = ecnt[e];
  const int rt = blockIdx.x, nt = blockIdx.y;
  if (rt * 128 >= cnt) return;
  __shared__ __align__(16) unsigned short As[128 * 64];
  __shared__ __align__(16) unsigned short Bs[128 * 64];
  const int tid = threadIdx.x;
  const int lane = tid & 63, wid = tid >> 6;
  const int eb = ebase[e];
  const int rsub = lane >> 3;
  const int csub = (lane & 7) * 8;
  const unsigned short* ap[4];
  const unsigned short* bp[4];
#pragma unroll
  for (int i = 0; i < 4; ++i) {
    const int r = (wid * 4 + i) * 8 + rsub;
    int lr = rt * 128 + r;
    if (lr >= cnt) lr = cnt - 1;
    ap[i] = hmid + (size_t)(eb + lr) * NF + csub;   // packed rows: no gather needed
    const int n = nt * 128 + r;
    bp[i] = wot + ((size_t)e * NH + n) * NF + csub;
  }
  const int wr = wid >> 1, wn = wid & 1;
  f32x4 acc[4][4] = {};

  for (int kf = 0; kf < NF; kf += 64) {
    __syncthreads();
#pragma unroll
    for (int i = 0; i < 4; ++i) gload16(ap[i] + kf, &As[(wid * 4 + i) * 8 * 64]);
#pragma unroll
    for (int i = 0; i < 4; ++i) gload16(bp[i] + kf, &Bs[(wid * 4 + i) * 8 * 64]);
    __syncthreads();
#pragma unroll
    for (int ks = 0; ks < 2; ++ks) {
      const int ko = ks * 32 + (lane >> 4) * 8;
      bf16x8 a[4], b[4];
#pragma unroll
      for (int mi = 0; mi < 4; ++mi)
        a[mi] = *reinterpret_cast<const bf16x8*>(&As[(wr * 64 + mi * 16 + (lane & 15)) * 64 + ko]);
#pragma unroll
      for (int ni = 0; ni < 4; ++ni)
        b[ni] = *reinterpret_cast<const bf16x8*>(&Bs[(wn * 64 + ni * 16 + (lane & 15)) * 64 + ko]);
#pragma unroll
      for (int mi = 0; mi < 4; ++mi)
#pragma unroll
        for (int ni = 0; ni < 4; ++ni)
          acc[mi][ni] = __builtin_amdgcn_mfma_f32_16x16x32_bf16(a[mi], b[ni], acc[mi][ni], 0, 0, 0);
    }
  }
#pragma unroll
  for (int mi = 0; mi < 4; ++mi)
#pragma unroll
    for (int ni = 0; ni < 4; ++ni)
#pragma unroll
      for (int r = 0; r < 4; ++r) {
        const int lr = rt * 128 + wr * 64 + mi * 16 + (lane >> 4) * 4 + r;
        if (lr >= cnt) continue;
        const int prow = eb + lr;
        const int tok = rowmap[prow];
        const float w = roww[prow];
        const int col = nt * 128 + wn * 64 + ni * 16 + (lane & 15);
        unsafeAtomicAdd(&out[(size_t)tok * NH + col], acc[mi][ni][r] * w);
      }
}

// ---------------- launch ----------------
extern "C" void kernel_launch(void* const* d_in, const int* in_sizes, int n_in,
                              void* d_out, int out_size, void* d_ws, size_t ws_size,
                              hipStream_t stream) {
  const float* x   = (const float*)d_in[0];
  const float* wrt = (const float*)d_in[1];
  const float* w0  = (const float*)d_in[2];
  const float* w1  = (const float*)d_in[3];
  const float* wo  = (const float*)d_in[4];
  float* out = (float*)d_out;

  char* ws = (char*)d_ws;
  size_t off = 0;
  auto carve = [&](size_t bytes) -> char* {
    char* p = ws + off;
    off = (off + bytes + 255) & ~(size_t)255;
    return p;
  };
  unsigned short* xb   = (unsigned short*)carve((size_t)NT * NH * 2);
  unsigned short* w0t  = (unsigned short*)carve((size_t)NE * NF * NH * 2);
  unsigned short* w1t  = (unsigned short*)carve((size_t)NE * NF * NH * 2);
  unsigned short* wot  = (unsigned short*)carve((size_t)NE * NH * NF * 2);
  unsigned short* hmid = (unsigned short*)carve((size_t)NROWS * NF * 2);
  int*   rowmap = (int*)carve(NROWS * 4);
  float* roww   = (float*)carve(NROWS * 4);
  int*   top_e  = (int*)carve(NT * 2 * 4);
  float* top_w  = (float*)carve(NT * 2 * 4);
  int*   cnt    = (int*)carve(256);
  int*   base   = (int*)carve(256);
  int*   cursor = (int*)carve(256);
  if (off > ws_size) return;  // workspace too small; fail loudly via wrong output

  hipMemsetAsync(cnt, 0, 256, stream);
  hipMemsetAsync(out, 0, (size_t)out_size * sizeof(float), stream);

  // conversions
  k_convert_x<<<(NT * NH / 4) / 256, 256, 0, stream>>>(x, xb);
  k_transpose_convert<<<dim3(NF / 32, NH / 32, NE), dim3(32, 8), 0, stream>>>(w0, w0t, NH, NF);
  k_transpose_convert<<<dim3(NF / 32, NH / 32, NE), dim3(32, 8), 0, stream>>>(w1, w1t, NH, NF);
  k_transpose_convert<<<dim3(NH / 32, NF / 32, NE), dim3(32, 8), 0, stream>>>(wo, wot, NF, NH);

  // routing
  k_router<<<NT / 4, 256, 0, stream>>>(x, wrt, top_e, top_w, cnt);
  k_prefix<<<1, 64, 0, stream>>>(cnt, base, cursor);
  k_scatter<<<NT / 256, 256, 0, stream>>>(top_e, top_w, cursor, rowmap, roww);

  // expert FFN (static worst-case grids; empty tiles exit immediately)
  k_gemm1<<<dim3(64, NF / 128, NE), 256, 0, stream>>>(xb, w0t, w1t, hmid, rowmap, base, cnt);
  k_gemm2<<<dim3(64, NH / 128, NE), 256, 0, stream>>>(hmid, wot, out, rowmap, roww, base, cnt);
}